// Round 2
// baseline (450.155 us; speedup 1.0000x reference)
//
#include <hip/hip_runtime.h>

constexpr int NL    = 48;
constexpr int SEQ   = 1024;
constexpr int BATCH = 512;

typedef float f2 __attribute__((ext_vector_type(2)));
typedef float f4 __attribute__((ext_vector_type(4)));

__device__ __forceinline__ f2 fma2(f2 a, f2 b, f2 c) {
    return __builtin_elementwise_fma(a, b, c);   // -> v_pk_fma_f32
}
__device__ __forceinline__ f2 max2(f2 a, f2 b) {
    return __builtin_elementwise_max(a, b);      // -> v_pk_max_f32
}

// One step of the linear-domain forward recurrence for ONE sequence.
// LDS broadcast: lane j owns v[j]; previous step wrote it to svl_[tid];
// this step reads the whole 48-vector back as 12 uniform ds_read_b128
// (conflict-free broadcast), does 24 v_pk_fma_f32 against the resident
// transition column pairs Ec2[], and writes the new v.
// RN_: renorm max is computed IN REGISTERS from the same broadcast values
// (v_pk_max tree, off the FMA critical path) -- replaces the 6-chained
// __shfl_xor butterfly (6 serial DS-pipe ops) of the previous version.
// rm_ = rcp(max(v_pre)) is folded into both mask paths; S_ += log(max).
#define CRF_STEP(T_, SLOT_, RN_, v_, S_, eb_, mb_, em_, svl_, sv4_) do {      \
    float ee_ = __expf(eb_[SLOT_]);                                           \
    int   mt_ = (int)((mb_ >> (SLOT_)) & 1);                                  \
    int   tn_ = (T_) + 8; if (tn_ > SEQ - 1) tn_ = SEQ - 1;                   \
    eb_[SLOT_] = em_[tn_ * NL + jc];                                          \
    f4 sv_[12];                                                               \
    _Pragma("unroll")                                                         \
    for (int g_ = 0; g_ < 12; ++g_) sv_[g_] = sv4_[g_];                       \
    f2 c0_ = {0.f, 0.f}, c1_ = {0.f, 0.f};                                    \
    f2 c2_ = {0.f, 0.f}, c3_ = {0.f, 0.f};                                    \
    _Pragma("unroll")                                                         \
    for (int g_ = 0; g_ < 12; g_ += 2) {                                      \
        c0_ = fma2(sv_[g_    ].xy, Ec2[2 * g_    ], c0_);                     \
        c1_ = fma2(sv_[g_    ].zw, Ec2[2 * g_ + 1], c1_);                     \
        c2_ = fma2(sv_[g_ + 1].xy, Ec2[2 * g_ + 2], c2_);                     \
        c3_ = fma2(sv_[g_ + 1].zw, Ec2[2 * g_ + 3], c3_);                     \
    }                                                                         \
    float rm_ = 1.0f;                                                         \
    if (RN_) {                                                                \
        f2 x0_ = max2(max2(sv_[0].xy,  sv_[0].zw),  max2(sv_[1].xy,  sv_[1].zw));  \
        f2 x1_ = max2(max2(sv_[2].xy,  sv_[2].zw),  max2(sv_[3].xy,  sv_[3].zw));  \
        f2 x2_ = max2(max2(sv_[4].xy,  sv_[4].zw),  max2(sv_[5].xy,  sv_[5].zw));  \
        f2 x3_ = max2(max2(sv_[6].xy,  sv_[6].zw),  max2(sv_[7].xy,  sv_[7].zw));  \
        f2 x4_ = max2(max2(sv_[8].xy,  sv_[8].zw),  max2(sv_[9].xy,  sv_[9].zw));  \
        f2 x5_ = max2(max2(sv_[10].xy, sv_[10].zw), max2(sv_[11].xy, sv_[11].zw)); \
        f2 y_  = max2(max2(x0_, x1_), max2(max2(x2_, x3_), max2(x4_, x5_)));  \
        float m_ = fmaxf(y_.x, y_.y);                                         \
        rm_ = __builtin_amdgcn_rcpf(m_);                                      \
        S_ += __logf(m_);                                                     \
    }                                                                         \
    f2 cs_ = (c0_ + c2_) + (c1_ + c3_);                                       \
    float acc_ = cs_.x + cs_.y;                                               \
    v_ = (mt_ ? acc_ * ee_ : v_) * rm_;                                       \
    svl_[tid] = v_;                                                           \
} while (0)

// Interleave one step of sequence A with one step of sequence B: while A's
// LDS round trip (ds_write -> 12 ds_read_b128 -> FMA tree) is in flight,
// the wave issues B's step, hiding the ~400-cycle per-seq chain latency.
#define CRF_PAIR(T_, SLOT_, RN_)                                              \
    CRF_STEP(T_, SLOT_, RN_, vA, SA, ebA, mbA, emA, svlA, sv4A);              \
    CRF_STEP(T_, SLOT_, RN_, vB, SB, ebB, mbB, emB, svlB, sv4B)

// Block = 192 threads, 256 blocks (1 block/CU): wave 0 runs the forward
// recurrence for TWO sequences (2*pb, 2*pb+1), waves 1-2 do the gold score
// (one sequence each).  amdgpu_waves_per_eu(1,1): 3 waves land on 3
// different SIMDs; the forward wave gets the full VGPR budget so Ec2[24]
// (shared by both sequences) plus both sequences' state stay in registers.
__global__ __launch_bounds__(192)
__attribute__((amdgpu_waves_per_eu(1, 1)))
void crf_fused(
    const float* __restrict__ emissions, const int* __restrict__ labels,
    const int* __restrict__ mask, const float* __restrict__ trans,
    const float* __restrict__ startt, const float* __restrict__ endt,
    float* __restrict__ gold_out, float* __restrict__ fwd_out)
{
    const int pb  = blockIdx.x;       // pair index
    const int tid = threadIdx.x;
    const int bA  = 2 * pb;
    const int bB  = 2 * pb + 1;

    // broadcast buffers for wave 0 only (waves 1-2 never touch LDS; a single
    // wave produces and consumes each buffer -> no barriers, DS is in-order).
    __shared__ alignas(16) float svl[2][64];

    if (tid < 64) {
        // ---------------- wave 0: forward algorithm, 2 sequences ----------
        const int  j   = tid;                  // lanes 48..63 idle mirrors
        const bool act = (j < NL);
        const int  jc  = act ? j : NL - 1;

        const float* emA = emissions + (size_t)bA * SEQ * NL;
        const float* emB = emissions + (size_t)bB * SEQ * NL;
        const int*   mkA = mask + bA * SEQ;
        const int*   mkB = mask + bB * SEQ;
        float* svlA = svl[0];
        float* svlB = svl[1];
        const f4* sv4A = reinterpret_cast<const f4*>(svlA);
        const f4* sv4B = reinterpret_cast<const f4*>(svlB);

        // E column jc as register pairs, shared by both sequences.
        f2 Ec2[24];
        #pragma unroll
        for (int k = 0; k < 24; ++k) {
            f2 e_;
            e_.x = __expf(trans[(2 * k    ) * NL + jc]);
            e_.y = __expf(trans[(2 * k + 1) * NL + jc]);
            Ec2[k] = e_;
        }

        // mask ballots: one vector load + __ballot per 8-step block per seq.
        int mvA = mkA[tid & 7];
        int mvB = mkB[tid & 7];
        unsigned long long mbA = __ballot(mvA != 0);   // bits for steps 0..7
        unsigned long long mbB = __ballot(mvB != 0);
        mvA = mkA[8 + (tid & 7)];                      // preload steps 8..15
        mvB = mkB[8 + (tid & 7)];

        // init: score0 = start + emit[0]; normalize by wave max (once).
        float s0A = act ? (startt[jc] + emA[jc]) : -3.0e38f;
        float s0B = act ? (startt[jc] + emB[jc]) : -3.0e38f;
        float m0A = s0A, m0B = s0B;
        #pragma unroll
        for (int o = 32; o; o >>= 1) {
            m0A = fmaxf(m0A, __shfl_xor(m0A, o));
            m0B = fmaxf(m0B, __shfl_xor(m0B, o));
        }
        float vA = act ? __expf(s0A - m0A) : 0.0f;  float SA = m0A;
        float vB = act ? __expf(s0B - m0B) : 0.0f;  float SB = m0B;
        svlA[tid] = vA;
        svlB[tid] = vB;

        // 8-deep emission prefetch rings.
        float ebA[8], ebB[8];
        #pragma unroll
        for (int t = 1; t <= 8; ++t) {
            ebA[t & 7] = emA[t * NL + jc];
            ebB[t & 7] = emB[t * NL + jc];
        }

        // peeled steps 1..7; renorm at step 5 (v from step 4).
        CRF_PAIR(1, 1, 0); CRF_PAIR(2, 2, 0); CRF_PAIR(3, 3, 0); CRF_PAIR(4, 4, 0);
        CRF_PAIR(5, 5, 1); CRF_PAIR(6, 6, 0); CRF_PAIR(7, 7, 0);

        // aligned chunks of 8: tb = 8,16,...,1016 covers t = 8..1023.
        // renorm at tb+0 and tb+4 -> every <=4 steps (fp32-safe growth).
        for (int tb = 8; tb <= SEQ - 8; tb += 8) {
            mbA = __ballot(mvA != 0);                 // mask bits for tb..tb+7
            mbB = __ballot(mvB != 0);
            int tm = tb + 8 + (tid & 7);              // prefetch next block
            if (tm > SEQ - 1) tm = SEQ - 1;
            mvA = mkA[tm];
            mvB = mkB[tm];
            CRF_PAIR(tb + 0, 0, 1);
            CRF_PAIR(tb + 1, 1, 0); CRF_PAIR(tb + 2, 2, 0); CRF_PAIR(tb + 3, 3, 0);
            CRF_PAIR(tb + 4, 4, 1);
            CRF_PAIR(tb + 5, 5, 0); CRF_PAIR(tb + 6, 6, 0); CRF_PAIR(tb + 7, 7, 0);
        }

        // fwd = S + log(sum_j v[j] * exp(end[j])) over active lanes.
        float et = __expf(endt[jc]);
        float wA = act ? vA * et : 0.0f;
        float wB = act ? vB * et : 0.0f;
        #pragma unroll
        for (int o = 32; o; o >>= 1) {
            wA += __shfl_xor(wA, o);
            wB += __shfl_xor(wB, o);
        }
        if (j == 0) {
            fwd_out[bA] = SA + __logf(wA);
            fwd_out[bB] = SB + __logf(wB);
        }
    } else {
        // ---------------- waves 1-2: gold score (one sequence each) -------
        const int  w   = (tid >> 6) - 1;            // 0 or 1
        const int  l   = tid & 63;
        const int  seq = 2 * pb + w;
        const int* lb  = labels + seq * SEQ;
        const int* mks = mask + seq * SEQ;
        const float* ems = emissions + (size_t)seq * SEQ * NL;

        float part = 0.0f; int mcnt = 0;
        for (int t = l; t < SEQ; t += 64) {
            int lt = lb[t];
            int mt = mks[t];
            mcnt += mt;
            if (t == 0) {
                part += startt[lt] + ems[lt];
            } else {
                float e  = ems[t * NL + lt];
                float tr = trans[lt * NL + lb[t - 1]];   // gold uses T[cur][prev]
                if (mt) part += e + tr;
            }
        }
        #pragma unroll
        for (int o = 32; o; o >>= 1) {
            part += __shfl_xor(part, o);
            mcnt += __shfl_xor(mcnt, o);
        }
        if (l == 0) {
            int len = mcnt - 1;
            gold_out[seq] = part + endt[lb[len]];
        }
    }
}

__global__ __launch_bounds__(64) void crf_reduce(
    const float* __restrict__ gold, const float* __restrict__ fwd,
    float* __restrict__ out)
{
    const int l = threadIdx.x;
    float s = 0.0f;
    for (int bIdx = l; bIdx < BATCH; bIdx += 64) s += fwd[bIdx] - gold[bIdx];
    #pragma unroll
    for (int o = 32; o; o >>= 1) s += __shfl_xor(s, o);
    if (l == 0) out[0] = s * (1.0f / (float)BATCH);
}

extern "C" void kernel_launch(void* const* d_in, const int* in_sizes, int n_in,
                              void* d_out, int out_size, void* d_ws, size_t ws_size,
                              hipStream_t stream) {
    const float* emissions = (const float*)d_in[0];
    const int*   labels    = (const int*)d_in[1];
    const int*   mask      = (const int*)d_in[2];
    const float* trans     = (const float*)d_in[3];
    const float* startt    = (const float*)d_in[4];
    const float* endt      = (const float*)d_in[5];
    float*       out       = (float*)d_out;
    float*       wsf       = (float*)d_ws;   // [0..512) gold, [512..1024) fwd

    crf_fused<<<BATCH / 2, 192, 0, stream>>>(emissions, labels, mask, trans,
                                             startt, endt, wsf, wsf + BATCH);
    crf_reduce<<<1, 64, 0, stream>>>(wsf, wsf + BATCH, out);
}